// Round 1
// baseline (429.072 us; speedup 1.0000x reference)
//
#include <hip/hip_runtime.h>
#include <math.h>

#define Bb 2
#define Nn 2048
#define Hh 256
#define NH 8
#define HD 32
#define NEDGE 65536
#define LN_EPS 1e-5f
#define MW 64          // mask words per row = N/32
#define RT 16          // rows per proj block

__global__ void zero_mask_kernel(unsigned int* mask) {
    int i = blockIdx.x * blockDim.x + threadIdx.x;
    if (i < Nn * MW) mask[i] = 0u;
}

__global__ void build_mask_kernel(const int* __restrict__ ei, unsigned int* __restrict__ mask) {
    int e = blockIdx.x * blockDim.x + threadIdx.x;
    if (e >= NEDGE) return;
    int src = ei[e];
    int dst = ei[NEDGE + e];
    atomicOr(&mask[src * MW + (dst >> 5)], 1u << (dst & 31));
}

// Q/K/V projection: y[row,col] = sum_d x[row,d] * W[col,d]
__global__ __launch_bounds__(256) void proj_kernel(
    const float* __restrict__ x,
    const float* __restrict__ Wq, const float* __restrict__ Wk, const float* __restrict__ Wv,
    float* __restrict__ Qb, float* __restrict__ Kb, float* __restrict__ Vb)
{
    __shared__ float xt[RT][Hh];
    int bid = blockIdx.x;
    int nrb = (Bb * Nn) / RT;
    int which = bid / nrb;
    int row0 = (bid % nrb) * RT;
    const float* W = (which == 0) ? Wq : ((which == 1) ? Wk : Wv);
    float* Ob = (which == 0) ? Qb : ((which == 1) ? Kb : Vb);
    int t = threadIdx.x;
    for (int r = 0; r < RT; ++r) xt[r][t] = x[(row0 + r) * Hh + t];
    __syncthreads();
    float acc[RT];
    #pragma unroll
    for (int r = 0; r < RT; ++r) acc[r] = 0.f;
    const float4* W4 = (const float4*)(W + t * Hh);
    for (int d4 = 0; d4 < Hh / 4; ++d4) {
        float4 w = W4[d4];
        #pragma unroll
        for (int r = 0; r < RT; ++r) {
            float4 xv = *(const float4*)&xt[r][d4 * 4];
            acc[r] += xv.x * w.x + xv.y * w.y + xv.z * w.z + xv.w * w.w;
        }
    }
    for (int r = 0; r < RT; ++r) Ob[(row0 + r) * Hh + t] = acc[r];
}

// Sparse masked attention: one 64-lane wave per (b, h, row).
__global__ __launch_bounds__(64) void attn_kernel(
    const float* __restrict__ Qb, const float* __restrict__ Kb, const float* __restrict__ Vb,
    const unsigned int* __restrict__ mask, float* __restrict__ attn)
{
    __shared__ int nbr[Nn];     // neighbor column indices (worst case N)
    __shared__ float sc[Nn];    // scores -> softmax weights
    int gid = blockIdx.x;
    int i = gid & (Nn - 1);
    int h = (gid >> 11) & (NH - 1);
    int b = gid >> 14;
    int lane = threadIdx.x;

    // extract dedup'd neighbor list from bitmask (one mask word per lane)
    unsigned int bits = mask[i * MW + lane];
    int cnt = __popc(bits);
    int incl = cnt;
    #pragma unroll
    for (int off = 1; off < 64; off <<= 1) {
        int v = __shfl_up(incl, off, 64);
        if (lane >= off) incl += v;
    }
    int nn = __shfl(incl, 63, 64);
    int idx = incl - cnt;
    unsigned int bb = bits;
    while (bb) {
        int bit = __ffs(bb) - 1;
        nbr[idx++] = lane * 32 + bit;
        bb &= bb - 1;
    }
    __syncthreads();

    int d = lane & 31;
    int half = lane >> 5;
    int qoff = (b * Nn + i) * Hh + h * HD;
    float outv = 0.f;
    if (nn > 0) {
        float q = Qb[qoff + d];
        const float scale = 0.17677669529663687f;  // 1/sqrt(32)
        // scores: each 32-lane half handles alternate neighbors
        for (int k = half; k < nn; k += 2) {
            int j = nbr[k];
            float kv = Kb[(b * Nn + j) * Hh + h * HD + d];
            float p = q * kv;
            #pragma unroll
            for (int m = 1; m < 32; m <<= 1) p += __shfl_xor(p, m, 64);
            if (d == 0) sc[k] = p * scale;
        }
        __syncthreads();
        // softmax over nn scores
        float mx = -1e30f;
        for (int k = lane; k < nn; k += 64) mx = fmaxf(mx, sc[k]);
        #pragma unroll
        for (int m = 1; m < 64; m <<= 1) mx = fmaxf(mx, __shfl_xor(mx, m, 64));
        float sum = 0.f;
        for (int k = lane; k < nn; k += 64) {
            float ev = __expf(sc[k] - mx);
            sc[k] = ev;
            sum += ev;
        }
        #pragma unroll
        for (int m = 1; m < 64; m <<= 1) sum += __shfl_xor(sum, m, 64);
        float inv = 1.f / sum;
        __syncthreads();
        // weighted V gather
        for (int k = half; k < nn; k += 2) {
            int j = nbr[k];
            outv += sc[k] * inv * Vb[(b * Nn + j) * Hh + h * HD + d];
        }
        outv += __shfl_xor(outv, 32, 64);
    }
    if (half == 0) attn[qoff + d] = outv;
}

// out = LayerNorm(attn @ Wo^T + x)
__global__ __launch_bounds__(256) void outln_kernel(
    const float* __restrict__ attn, const float* __restrict__ x,
    const float* __restrict__ Wo, const float* __restrict__ gamma,
    const float* __restrict__ beta, float* __restrict__ out)
{
    __shared__ float ar[Hh];
    __shared__ float red[4];
    int row = blockIdx.x;
    int t = threadIdx.x;
    ar[t] = attn[row * Hh + t];
    __syncthreads();
    float acc = 0.f;
    const float4* W4 = (const float4*)(Wo + t * Hh);
    const float4* a4 = (const float4*)ar;
    for (int d4 = 0; d4 < Hh / 4; ++d4) {
        float4 w = W4[d4];
        float4 av = a4[d4];
        acc += av.x * w.x + av.y * w.y + av.z * w.z + av.w * w.w;
    }
    float y = acc + x[row * Hh + t];
    // mean
    float v = y;
    #pragma unroll
    for (int m = 1; m < 64; m <<= 1) v += __shfl_xor(v, m, 64);
    int wid = t >> 6;
    if ((t & 63) == 0) red[wid] = v;
    __syncthreads();
    float mu = (red[0] + red[1] + red[2] + red[3]) * (1.f / Hh);
    float dv = y - mu;
    float vv = dv * dv;
    #pragma unroll
    for (int m = 1; m < 64; m <<= 1) vv += __shfl_xor(vv, m, 64);
    __syncthreads();
    if ((t & 63) == 0) red[wid] = vv;
    __syncthreads();
    float var = (red[0] + red[1] + red[2] + red[3]) * (1.f / Hh);
    out[row * Hh + t] = dv * rsqrtf(var + LN_EPS) * gamma[t] + beta[t];
}

extern "C" void kernel_launch(void* const* d_in, const int* in_sizes, int n_in,
                              void* d_out, int out_size, void* d_ws, size_t ws_size,
                              hipStream_t stream) {
    const float* x     = (const float*)d_in[0];
    const int*   ei    = (const int*)d_in[1];
    // d_in[2] = edge_weights: unused by the reference
    const float* Wq    = (const float*)d_in[3];
    const float* Wk    = (const float*)d_in[4];
    const float* Wv    = (const float*)d_in[5];
    const float* Wo    = (const float*)d_in[6];
    const float* gamma = (const float*)d_in[7];
    const float* beta  = (const float*)d_in[8];
    float* out = (float*)d_out;

    const int NTOK = Bb * Nn * Hh;  // 1048576
    float* Qb   = (float*)d_ws;
    float* Kb   = Qb + NTOK;
    float* Vb   = Kb + NTOK;
    float* attn = Vb + NTOK;
    unsigned int* mask = (unsigned int*)(attn + NTOK);

    hipLaunchKernelGGL(zero_mask_kernel, dim3((Nn * MW + 255) / 256), dim3(256), 0, stream, mask);
    hipLaunchKernelGGL(build_mask_kernel, dim3(NEDGE / 256), dim3(256), 0, stream, ei, mask);
    hipLaunchKernelGGL(proj_kernel, dim3(3 * (Bb * Nn) / RT), dim3(256), 0, stream,
                       x, Wq, Wk, Wv, Qb, Kb, Vb);
    hipLaunchKernelGGL(attn_kernel, dim3(Bb * NH * Nn), dim3(64), 0, stream,
                       Qb, Kb, Vb, mask, attn);
    hipLaunchKernelGGL(outln_kernel, dim3(Bb * Nn), dim3(256), 0, stream,
                       attn, x, Wo, gamma, beta, out);
}

// Round 2
// 149.904 us; speedup vs baseline: 2.8623x; 2.8623x over previous
//
#include <hip/hip_runtime.h>
#include <math.h>

#define Bb 2
#define Nn 2048
#define Hh 256
#define NH 8
#define HD 32
#define NEDGE 65536
#define LN_EPS 1e-5f
#define MW 64          // mask words per row = N/32

__global__ void zero_mask_kernel(unsigned int* mask) {
    int i = blockIdx.x * blockDim.x + threadIdx.x;
    if (i < Nn * MW) mask[i] = 0u;
}

__global__ void build_mask_kernel(const int* __restrict__ ei, unsigned int* __restrict__ mask) {
    int e = blockIdx.x * blockDim.x + threadIdx.x;
    if (e >= NEDGE) return;
    int src = ei[e];
    int dst = ei[NEDGE + e];
    atomicOr(&mask[src * MW + (dst >> 5)], 1u << (dst & 31));
}

// ---------------------------------------------------------------------------
// Register-tiled fp32 GEMM: C[m][n] = sum_d A[m][d] * W[n][d]  (torch Linear)
// 64x64 tile per 256-thread block, 4x4 per thread, K-tiles of 32.
// Both tiles stored k-major in LDS so the inner loop is 2x ds_read_b128 : 16 FMA.
// ---------------------------------------------------------------------------
#define TK 32
#define LDP 68   // padded row length (floats); 68%4==0 keeps float4 alignment

__device__ __forceinline__ void gemm_tile_body(
    const float* __restrict__ A, const float* __restrict__ W,
    float As[TK][LDP], float Ws[TK][LDP],
    int m0, int n0, float4 acc[4])
{
    int t = threadIdx.x;
    int lrow = t >> 2;        // 0..63 : which tile row this thread loads
    int lkq = t & 3;          // 0..3  : which 8-float k-segment
    int tx = t & 15;          // output col group
    int ty = t >> 4;          // output row group
    for (int k0 = 0; k0 < Hh; k0 += TK) {
        const float4* ap = (const float4*)(A + (m0 + lrow) * Hh + k0 + lkq * 8);
        const float4* wp = (const float4*)(W + (n0 + lrow) * Hh + k0 + lkq * 8);
        float4 a0 = ap[0], a1 = ap[1];
        float4 w0 = wp[0], w1 = wp[1];
        __syncthreads();   // previous iteration's reads complete
        int kb = lkq * 8;
        As[kb + 0][lrow] = a0.x; As[kb + 1][lrow] = a0.y;
        As[kb + 2][lrow] = a0.z; As[kb + 3][lrow] = a0.w;
        As[kb + 4][lrow] = a1.x; As[kb + 5][lrow] = a1.y;
        As[kb + 6][lrow] = a1.z; As[kb + 7][lrow] = a1.w;
        Ws[kb + 0][lrow] = w0.x; Ws[kb + 1][lrow] = w0.y;
        Ws[kb + 2][lrow] = w0.z; Ws[kb + 3][lrow] = w0.w;
        Ws[kb + 4][lrow] = w1.x; Ws[kb + 5][lrow] = w1.y;
        Ws[kb + 6][lrow] = w1.z; Ws[kb + 7][lrow] = w1.w;
        __syncthreads();
        #pragma unroll
        for (int kk = 0; kk < TK; ++kk) {
            float4 a = *(const float4*)&As[kk][ty * 4];
            float4 w = *(const float4*)&Ws[kk][tx * 4];
            acc[0].x = fmaf(a.x, w.x, acc[0].x); acc[0].y = fmaf(a.x, w.y, acc[0].y);
            acc[0].z = fmaf(a.x, w.z, acc[0].z); acc[0].w = fmaf(a.x, w.w, acc[0].w);
            acc[1].x = fmaf(a.y, w.x, acc[1].x); acc[1].y = fmaf(a.y, w.y, acc[1].y);
            acc[1].z = fmaf(a.y, w.z, acc[1].z); acc[1].w = fmaf(a.y, w.w, acc[1].w);
            acc[2].x = fmaf(a.z, w.x, acc[2].x); acc[2].y = fmaf(a.z, w.y, acc[2].y);
            acc[2].z = fmaf(a.z, w.z, acc[2].z); acc[2].w = fmaf(a.z, w.w, acc[2].w);
            acc[3].x = fmaf(a.w, w.x, acc[3].x); acc[3].y = fmaf(a.w, w.y, acc[3].y);
            acc[3].z = fmaf(a.w, w.z, acc[3].z); acc[3].w = fmaf(a.w, w.w, acc[3].w);
        }
    }
}

__global__ __launch_bounds__(256) void qkv_gemm_kernel(
    const float* __restrict__ x,
    const float* __restrict__ Wq, const float* __restrict__ Wk, const float* __restrict__ Wv,
    float* __restrict__ Qb, float* __restrict__ Kb, float* __restrict__ Vb)
{
    __shared__ float As[TK][LDP];
    __shared__ float Ws[TK][LDP];
    int m0 = blockIdx.x * 64;
    int n0 = blockIdx.y * 64;
    int which = blockIdx.z;
    const float* W = (which == 0) ? Wq : ((which == 1) ? Wk : Wv);
    float* Ob = (which == 0) ? Qb : ((which == 1) ? Kb : Vb);
    float4 acc[4] = {{0,0,0,0},{0,0,0,0},{0,0,0,0},{0,0,0,0}};
    gemm_tile_body(x, W, As, Ws, m0, n0, acc);
    int tx = threadIdx.x & 15, ty = threadIdx.x >> 4;
    #pragma unroll
    for (int r = 0; r < 4; ++r)
        *(float4*)(Ob + (m0 + ty * 4 + r) * Hh + n0 + tx * 4) = acc[r];
}

// y = attn @ Wo^T + x  (residual fused); LN done by separate kernel in-place on d_out
__global__ __launch_bounds__(256) void out_gemm_kernel(
    const float* __restrict__ attn, const float* __restrict__ Wo,
    const float* __restrict__ x, float* __restrict__ y)
{
    __shared__ float As[TK][LDP];
    __shared__ float Ws[TK][LDP];
    int m0 = blockIdx.x * 64;
    int n0 = blockIdx.y * 64;
    float4 acc[4] = {{0,0,0,0},{0,0,0,0},{0,0,0,0},{0,0,0,0}};
    gemm_tile_body(attn, Wo, As, Ws, m0, n0, acc);
    int tx = threadIdx.x & 15, ty = threadIdx.x >> 4;
    #pragma unroll
    for (int r = 0; r < 4; ++r) {
        float4 res = *(const float4*)(x + (m0 + ty * 4 + r) * Hh + n0 + tx * 4);
        acc[r].x += res.x; acc[r].y += res.y; acc[r].z += res.z; acc[r].w += res.w;
        *(float4*)(y + (m0 + ty * 4 + r) * Hh + n0 + tx * 4) = acc[r];
    }
}

// ---------------------------------------------------------------------------
// Sparse attention: one 256-thread block per (b, row). All 8 heads in parallel.
// thread t -> head h = t>>5, lane-in-head dl = t&31 (dual role: neighbor index
// for scores, d-component for PV). Online softmax over chunks of 32 neighbors.
// ---------------------------------------------------------------------------
__global__ __launch_bounds__(256) void attn2_kernel(
    const float* __restrict__ Qb, const float* __restrict__ Kb, const float* __restrict__ Vb,
    const unsigned int* __restrict__ mask, float* __restrict__ attn)
{
    __shared__ int nbr[Nn];       // dedup'd neighbor list (worst case N)
    __shared__ float qs[Hh];      // this row's Q (all heads)
    __shared__ float scw[Hh];     // softmax weights for current chunk [h][32]
    __shared__ int nn_sh;
    int gid = blockIdx.x;         // 0..4095
    int i = gid & (Nn - 1);
    int b = gid >> 11;
    int t = threadIdx.x;
    int h = t >> 5, dl = t & 31;

    // wave 0 extracts the neighbor list from the bitmask
    if (t < 64) {
        unsigned int bits = mask[i * MW + t];
        int cnt = __popc(bits);
        int incl = cnt;
        #pragma unroll
        for (int off = 1; off < 64; off <<= 1) {
            int v = __shfl_up(incl, off, 64);
            if (t >= off) incl += v;
        }
        int idx = incl - cnt;
        unsigned int bb = bits;
        while (bb) {
            int bit = __ffs(bb) - 1;
            nbr[idx++] = t * 32 + bit;
            bb &= bb - 1;
        }
        if (t == 63) nn_sh = incl;
    }
    qs[t] = Qb[(b * Nn + i) * Hh + t];
    __syncthreads();
    int nn = nn_sh;

    float m_run = -1e30f, l_run = 0.f, o = 0.f;
    const float scale = 0.17677669529663687f;  // 1/sqrt(32)
    int nch = (nn + 31) >> 5;
    for (int c = 0; c < nch; ++c) {
        int k = (c << 5) + dl;
        float s = -1e30f;
        if (k < nn) {
            int j = nbr[k];
            const float4* kp = (const float4*)(Kb + ((b << 11) + j) * Hh + (h << 5));
            const float4* qp = (const float4*)(qs + (h << 5));
            float acc = 0.f;
            #pragma unroll
            for (int u = 0; u < 8; ++u) {
                float4 kv = kp[u];
                float4 qv = qp[u];
                acc = fmaf(kv.x, qv.x, acc);
                acc = fmaf(kv.y, qv.y, acc);
                acc = fmaf(kv.z, qv.z, acc);
                acc = fmaf(kv.w, qv.w, acc);
            }
            s = acc * scale;
        }
        // per-head (32-lane) max reduce
        float mc = s;
        #pragma unroll
        for (int m = 1; m < 32; m <<= 1) mc = fmaxf(mc, __shfl_xor(mc, m, 64));
        float m_new = fmaxf(m_run, mc);
        float w = __expf(s - m_new);        // s=-1e30 underflows to 0
        float sum = w;
        #pragma unroll
        for (int m = 1; m < 32; m <<= 1) sum += __shfl_xor(sum, m, 64);
        float alpha = __expf(m_run - m_new);  // first chunk: exp(-1e30)=0
        l_run = l_run * alpha + sum;
        m_run = m_new;
        __syncthreads();       // previous chunk's scw reads complete
        scw[t] = w;
        __syncthreads();
        o *= alpha;
        int lim = min(32, nn - (c << 5));
        for (int kl = 0; kl < lim; ++kl) {
            int j = nbr[(c << 5) + kl];
            o = fmaf(scw[(h << 5) + kl], Vb[((b << 11) + j) * Hh + t], o);
        }
    }
    float inv = (l_run > 0.f) ? 1.f / l_run : 0.f;
    attn[(b * Nn + i) * Hh + t] = o * inv;
}

// In-place LayerNorm over rows of y (one wave per row, float4 per lane)
__global__ __launch_bounds__(64) void ln_kernel(
    float* __restrict__ y, const float* __restrict__ gamma, const float* __restrict__ beta)
{
    int row = blockIdx.x;
    int lane = threadIdx.x;
    float4 v = *(const float4*)(y + row * Hh + lane * 4);
    float sum = v.x + v.y + v.z + v.w;
    #pragma unroll
    for (int m = 1; m < 64; m <<= 1) sum += __shfl_xor(sum, m, 64);
    float mu = sum * (1.f / Hh);
    float4 d = {v.x - mu, v.y - mu, v.z - mu, v.w - mu};
    float ss = d.x * d.x + d.y * d.y + d.z * d.z + d.w * d.w;
    #pragma unroll
    for (int m = 1; m < 64; m <<= 1) ss += __shfl_xor(ss, m, 64);
    float r = rsqrtf(ss * (1.f / Hh) + LN_EPS);
    float4 g = *(const float4*)(gamma + lane * 4);
    float4 bt = *(const float4*)(beta + lane * 4);
    float4 o = {d.x * r * g.x + bt.x, d.y * r * g.y + bt.y,
                d.z * r * g.z + bt.z, d.w * r * g.w + bt.w};
    *(float4*)(y + row * Hh + lane * 4) = o;
}

extern "C" void kernel_launch(void* const* d_in, const int* in_sizes, int n_in,
                              void* d_out, int out_size, void* d_ws, size_t ws_size,
                              hipStream_t stream) {
    const float* x     = (const float*)d_in[0];
    const int*   ei    = (const int*)d_in[1];
    // d_in[2] = edge_weights: unused by the reference
    const float* Wq    = (const float*)d_in[3];
    const float* Wk    = (const float*)d_in[4];
    const float* Wv    = (const float*)d_in[5];
    const float* Wo    = (const float*)d_in[6];
    const float* gamma = (const float*)d_in[7];
    const float* beta  = (const float*)d_in[8];
    float* out = (float*)d_out;

    const int NTOK = Bb * Nn * Hh;  // 1048576
    float* Qb   = (float*)d_ws;
    float* Kb   = Qb + NTOK;
    float* Vb   = Kb + NTOK;
    float* attn = Vb + NTOK;
    unsigned int* mask = (unsigned int*)(attn + NTOK);

    hipLaunchKernelGGL(zero_mask_kernel, dim3((Nn * MW + 255) / 256), dim3(256), 0, stream, mask);
    hipLaunchKernelGGL(build_mask_kernel, dim3(NEDGE / 256), dim3(256), 0, stream, ei, mask);
    hipLaunchKernelGGL(qkv_gemm_kernel, dim3((Bb * Nn) / 64, Hh / 64, 3), dim3(256), 0, stream,
                       x, Wq, Wk, Wv, Qb, Kb, Vb);
    hipLaunchKernelGGL(attn2_kernel, dim3(Bb * Nn), dim3(256), 0, stream,
                       Qb, Kb, Vb, mask, attn);
    hipLaunchKernelGGL(out_gemm_kernel, dim3((Bb * Nn) / 64, Hh / 64), dim3(256), 0, stream,
                       attn, Wo, x, out);
    hipLaunchKernelGGL(ln_kernel, dim3(Bb * Nn), dim3(64), 0, stream,
                       out, gamma, beta);
}

// Round 3
// 145.286 us; speedup vs baseline: 2.9533x; 1.0318x over previous
//
#include <hip/hip_runtime.h>
#include <math.h>

#define Bb 2
#define Nn 2048
#define Hh 256
#define NH 8
#define HD 32
#define NEDGE 65536
#define LN_EPS 1e-5f
#define MW 64          // mask words per row = N/32

typedef __bf16 bf16_t;
typedef bf16_t bf16x8 __attribute__((ext_vector_type(8)));
typedef float f32x4 __attribute__((ext_vector_type(4)));

__global__ void build_mask_kernel(const int* __restrict__ ei, unsigned int* __restrict__ mask) {
    int e = blockIdx.x * blockDim.x + threadIdx.x;
    if (e >= NEDGE) return;
    int src = ei[e];
    int dst = ei[NEDGE + e];
    atomicOr(&mask[src * MW + (dst >> 5)], 1u << (dst & 31));
}

// ---------------------------------------------------------------------------
// bf16 MFMA GEMM: C[m][n] = sum_k A[m][k] * W[n][k]  (A,W fp32 in global,
// converted to bf16 during LDS staging; fp32 MFMA accumulate).
// Block tile 128x64, BK=64, 4 waves in 2x2; each wave 64x32 via 4x2 mfma
// 16x16x32 tiles. LDA=88 bf16 (176B rows): fragment reads 2-way conflict only.
// ---------------------------------------------------------------------------
#define LDA 88
#define BM 128
#define BN 64
#define BK 64

template<bool QKV>
__global__ __launch_bounds__(256) void mfma_gemm_kernel(
    const float* __restrict__ A,
    const float* __restrict__ W0, const float* __restrict__ W1, const float* __restrict__ W2,
    float* __restrict__ O0, float* __restrict__ O1, float* __restrict__ O2,
    const float* __restrict__ resid)
{
    __shared__ bf16_t As[BM * LDA];
    __shared__ bf16_t Ws[BN * LDA];
    int t = threadIdx.x;
    int lane = t & 63;
    int w = t >> 6;
    int wm = w & 1, wn = w >> 1;
    int m0 = blockIdx.x * BM;
    int n0 = blockIdx.y * BN;
    const float* W;
    int nw0;
    if (QKV) {
        int which = blockIdx.y >> 2;        // BN=64, W boundary every 4 blocks
        W = (which == 0) ? W0 : ((which == 1) ? W1 : W2);
        nw0 = n0 & 255;
    } else {
        W = W0;
        nw0 = n0;
    }
    f32x4 acc[4][2];
    f32x4 zero = {0.f, 0.f, 0.f, 0.f};
    #pragma unroll
    for (int i = 0; i < 4; ++i)
        #pragma unroll
        for (int j = 0; j < 2; ++j) acc[i][j] = zero;

    int arow = t >> 4;          // 0..15
    int acol = (t & 15) << 2;   // float4 col within 64-wide k-slice
    int ml = lane & 15, quad = lane >> 4;

    for (int k0 = 0; k0 < Hh; k0 += BK) {
        float4 av[8], wv[4];
        #pragma unroll
        for (int u = 0; u < 8; ++u)
            av[u] = *(const float4*)(A + (size_t)(m0 + u * 16 + arow) * Hh + k0 + acol);
        #pragma unroll
        for (int u = 0; u < 4; ++u)
            wv[u] = *(const float4*)(W + (size_t)(nw0 + u * 16 + arow) * Hh + k0 + acol);
        __syncthreads();   // previous iteration's fragment reads complete
        #pragma unroll
        for (int u = 0; u < 8; ++u) {
            bf16_t* p = &As[(u * 16 + arow) * LDA + acol];
            p[0] = (bf16_t)av[u].x; p[1] = (bf16_t)av[u].y;
            p[2] = (bf16_t)av[u].z; p[3] = (bf16_t)av[u].w;
        }
        #pragma unroll
        for (int u = 0; u < 4; ++u) {
            bf16_t* p = &Ws[(u * 16 + arow) * LDA + acol];
            p[0] = (bf16_t)wv[u].x; p[1] = (bf16_t)wv[u].y;
            p[2] = (bf16_t)wv[u].z; p[3] = (bf16_t)wv[u].w;
        }
        __syncthreads();
        #pragma unroll
        for (int kk = 0; kk < BK; kk += 32) {
            bf16x8 bf[2];
            #pragma unroll
            for (int sn = 0; sn < 2; ++sn)
                bf[sn] = *(const bf16x8*)&Ws[(wn * 32 + sn * 16 + ml) * LDA + kk + quad * 8];
            #pragma unroll
            for (int sm = 0; sm < 4; ++sm) {
                bf16x8 af = *(const bf16x8*)&As[(wm * 64 + sm * 16 + ml) * LDA + kk + quad * 8];
                acc[sm][0] = __builtin_amdgcn_mfma_f32_16x16x32_bf16(af, bf[0], acc[sm][0], 0, 0, 0);
                acc[sm][1] = __builtin_amdgcn_mfma_f32_16x16x32_bf16(af, bf[1], acc[sm][1], 0, 0, 0);
            }
        }
    }
    // epilogue: C/D layout col=lane&15, row=(lane>>4)*4+reg  [m89-verified]
    #pragma unroll
    for (int sm = 0; sm < 4; ++sm)
        #pragma unroll
        for (int sn = 0; sn < 2; ++sn)
            #pragma unroll
            for (int r = 0; r < 4; ++r) {
                int mg = m0 + wm * 64 + sm * 16 + quad * 4 + r;
                int ng = n0 + wn * 32 + sn * 16 + ml;
                float v = acc[sm][sn][r];
                if (QKV) {
                    int which = ng >> 8;
                    float* Ob = (which == 0) ? O0 : ((which == 1) ? O1 : O2);
                    Ob[(size_t)mg * Hh + (ng & 255)] = v;
                } else {
                    O0[(size_t)mg * Hh + ng] = v + resid[(size_t)mg * Hh + ng];
                }
            }
}

// ---------------------------------------------------------------------------
// Sparse attention: one 256-thread block per (b, row). thread t: head h=t>>5,
// dl=t&31. K-chunk (32 rows) staged to LDS with coalesced 1KB wave loads and
// XOR swizzle (physical float4-group = (g + row) & 63) -> conflict-free.
// ---------------------------------------------------------------------------
__global__ __launch_bounds__(256) void attn3_kernel(
    const float* __restrict__ Qb, const float* __restrict__ Kb, const float* __restrict__ Vb,
    const unsigned int* __restrict__ mask, float* __restrict__ attn)
{
    __shared__ int nbr[Nn];            // dedup'd neighbor list
    __shared__ float qs[Hh];
    __shared__ float scw[Hh];
    __shared__ float Ks[32][256];      // swizzled K chunk
    __shared__ int nn_sh;
    int gid = blockIdx.x;
    int i = gid & (Nn - 1);
    int b = gid >> 11;
    int t = threadIdx.x;
    int h = t >> 5, dl = t & 31;
    int wv = t >> 6, lane = t & 63;

    if (t < 64) {   // wave 0: extract dedup'd neighbor list from bitmask
        unsigned int bits = mask[i * MW + t];
        int cnt = __popc(bits);
        int incl = cnt;
        #pragma unroll
        for (int off = 1; off < 64; off <<= 1) {
            int v = __shfl_up(incl, off, 64);
            if (t >= off) incl += v;
        }
        int idx = incl - cnt;
        unsigned int bb = bits;
        while (bb) {
            int bit = __ffs(bb) - 1;
            nbr[idx++] = t * 32 + bit;
            bb &= bb - 1;
        }
        if (t == 63) nn_sh = incl;
    }
    qs[t] = Qb[((size_t)(b * Nn + i)) * Hh + t];
    __syncthreads();
    int nn = nn_sh;

    float m_run = -1e30f, l_run = 0.f, o = 0.f;
    const float scale = 0.17677669529663687f;  // 1/sqrt(32)
    int nch = (nn + 31) >> 5;
    for (int c = 0; c < nch; ++c) {
        int base = c << 5;
        int lim = min(32, nn - base);
        __syncthreads();   // prev chunk's Ks/scw readers done
        // stage K chunk: wave wv loads rows wv, wv+4, ... fully coalesced (1KB/inst)
        #pragma unroll
        for (int s = 0; s < 8; ++s) {
            int r = wv + (s << 2);
            if (r < lim) {
                int j = nbr[base + r];
                float4 kv = *(const float4*)(Kb + ((size_t)((b << 11) + j)) * Hh + (lane << 2));
                *(float4*)&Ks[r][((lane + r) & 63) << 2] = kv;
            }
        }
        __syncthreads();
        float s = -1e30f;
        if (dl < lim) {
            const float4* qp = (const float4*)&qs[h << 5];
            float acc = 0.f;
            #pragma unroll
            for (int u = 0; u < 8; ++u) {
                int g = (h << 3) + u;
                float4 kv = *(const float4*)&Ks[dl][((g + dl) & 63) << 2];
                float4 qv = qp[u];
                acc = fmaf(kv.x, qv.x, acc);
                acc = fmaf(kv.y, qv.y, acc);
                acc = fmaf(kv.z, qv.z, acc);
                acc = fmaf(kv.w, qv.w, acc);
            }
            s = acc * scale;
        }
        float mc = s;
        #pragma unroll
        for (int m = 1; m < 32; m <<= 1) mc = fmaxf(mc, __shfl_xor(mc, m, 64));
        float m_new = fmaxf(m_run, mc);
        float wgt = __expf(s - m_new);
        float sum = wgt;
        #pragma unroll
        for (int m = 1; m < 32; m <<= 1) sum += __shfl_xor(sum, m, 64);
        float alpha = __expf(m_run - m_new);
        l_run = l_run * alpha + sum;
        m_run = m_new;
        scw[t] = wgt;
        __syncthreads();
        o *= alpha;
        for (int kl = 0; kl < lim; ++kl) {
            int j = nbr[base + kl];
            o = fmaf(scw[(h << 5) + kl], Vb[((size_t)((b << 11) + j)) * Hh + t], o);
        }
    }
    float inv = (l_run > 0.f) ? 1.f / l_run : 0.f;
    attn[((size_t)(b * Nn + i)) * Hh + t] = o * inv;
}

// In-place LayerNorm: 4 rows per block, one wave per row.
__global__ __launch_bounds__(256) void ln_kernel(
    float* __restrict__ y, const float* __restrict__ gamma, const float* __restrict__ beta)
{
    int row = blockIdx.x * 4 + (threadIdx.x >> 6);
    int lane = threadIdx.x & 63;
    float4 v = *(const float4*)(y + (size_t)row * Hh + lane * 4);
    float sum = v.x + v.y + v.z + v.w;
    #pragma unroll
    for (int m = 1; m < 64; m <<= 1) sum += __shfl_xor(sum, m, 64);
    float mu = sum * (1.f / Hh);
    float4 d = {v.x - mu, v.y - mu, v.z - mu, v.w - mu};
    float ss = d.x * d.x + d.y * d.y + d.z * d.z + d.w * d.w;
    #pragma unroll
    for (int m = 1; m < 64; m <<= 1) ss += __shfl_xor(ss, m, 64);
    float r = rsqrtf(ss * (1.f / Hh) + LN_EPS);
    float4 g = *(const float4*)(gamma + lane * 4);
    float4 bt = *(const float4*)(beta + lane * 4);
    float4 o = {d.x * r * g.x + bt.x, d.y * r * g.y + bt.y,
                d.z * r * g.z + bt.z, d.w * r * g.w + bt.w};
    *(float4*)(y + (size_t)row * Hh + lane * 4) = o;
}

extern "C" void kernel_launch(void* const* d_in, const int* in_sizes, int n_in,
                              void* d_out, int out_size, void* d_ws, size_t ws_size,
                              hipStream_t stream) {
    const float* x     = (const float*)d_in[0];
    const int*   ei    = (const int*)d_in[1];
    // d_in[2] = edge_weights: unused by the reference
    const float* Wq    = (const float*)d_in[3];
    const float* Wk    = (const float*)d_in[4];
    const float* Wv    = (const float*)d_in[5];
    const float* Wo    = (const float*)d_in[6];
    const float* gamma = (const float*)d_in[7];
    const float* beta  = (const float*)d_in[8];
    float* out = (float*)d_out;

    const int NTOK = Bb * Nn * Hh;  // 1048576
    float* Qb   = (float*)d_ws;
    float* Kb   = Qb + NTOK;
    float* Vb   = Kb + NTOK;
    float* attn = Vb + NTOK;
    unsigned int* mask = (unsigned int*)(attn + NTOK);

    hipMemsetAsync(mask, 0, Nn * MW * sizeof(unsigned int), stream);
    hipLaunchKernelGGL(build_mask_kernel, dim3(NEDGE / 256), dim3(256), 0, stream, ei, mask);
    hipLaunchKernelGGL((mfma_gemm_kernel<true>), dim3((Bb * Nn) / BM, (3 * Hh) / BN), dim3(256), 0, stream,
                       x, Wq, Wk, Wv, Qb, Kb, Vb, (const float*)nullptr);
    hipLaunchKernelGGL(attn3_kernel, dim3(Bb * Nn), dim3(256), 0, stream,
                       Qb, Kb, Vb, mask, attn);
    hipLaunchKernelGGL((mfma_gemm_kernel<false>), dim3((Bb * Nn) / BM, Hh / BN), dim3(256), 0, stream,
                       attn, Wo, (const float*)nullptr, (const float*)nullptr,
                       out, (float*)nullptr, (float*)nullptr, x);
    hipLaunchKernelGGL(ln_kernel, dim3((Bb * Nn) / 4), dim3(256), 0, stream,
                       out, gamma, beta);
}

// Round 4
// 119.950 us; speedup vs baseline: 3.5771x; 1.2112x over previous
//
#include <hip/hip_runtime.h>
#include <math.h>

#define Bb 2
#define Nn 2048
#define Hh 256
#define NH 8
#define HD 32
#define NEDGE 65536
#define LN_EPS 1e-5f
#define MW 64          // mask words per row = N/32

typedef __bf16 bf16_t;
typedef bf16_t bf16x8 __attribute__((ext_vector_type(8)));
typedef bf16_t bf16x4 __attribute__((ext_vector_type(4)));
typedef float f32x4 __attribute__((ext_vector_type(4)));

__global__ void build_mask_kernel(const int* __restrict__ ei, unsigned int* __restrict__ mask) {
    int e = blockIdx.x * blockDim.x + threadIdx.x;
    if (e >= NEDGE) return;
    int src = ei[e];
    int dst = ei[NEDGE + e];
    atomicOr(&mask[src * MW + (dst >> 5)], 1u << (dst & 31));
}

// one-shot fp32 -> bf16 conversion of x and the four weight matrices
__global__ __launch_bounds__(256) void cvt_bf16_kernel(
    const float* __restrict__ s0, const float* __restrict__ s1, const float* __restrict__ s2,
    const float* __restrict__ s3, const float* __restrict__ s4,
    bf16_t* __restrict__ d0, bf16_t* __restrict__ d1, bf16_t* __restrict__ d2,
    bf16_t* __restrict__ d3, bf16_t* __restrict__ d4)
{
    int which = blockIdx.y;
    const float* s = (which == 0) ? s0 : (which == 1) ? s1 : (which == 2) ? s2 : (which == 3) ? s3 : s4;
    bf16_t* d = (which == 0) ? d0 : (which == 1) ? d1 : (which == 2) ? d2 : (which == 3) ? d3 : d4;
    int n4 = (which == 0) ? (Bb * Nn * Hh / 4) : (Hh * Hh / 4);
    int i = blockIdx.x * blockDim.x + threadIdx.x;
    if (i >= n4) return;
    float4 v = ((const float4*)s)[i];
    bf16x4 o = {(bf16_t)v.x, (bf16_t)v.y, (bf16_t)v.z, (bf16_t)v.w};
    ((bf16x4*)d)[i] = o;
}

// ---------------------------------------------------------------------------
// bf16 MFMA GEMM (inputs pre-converted): C[m][n] = sum_k A[m][k]*W[n][k]
// 64x64 tile, BK=64, 4 waves 2x2 (each 32x32 = 2x2 mfma 16x16x32 tiles).
// ---------------------------------------------------------------------------
#define LDA2 72

__global__ __launch_bounds__(256) void qkv_gemm2_kernel(
    const bf16_t* __restrict__ xb,
    const bf16_t* __restrict__ Wqb, const bf16_t* __restrict__ Wkb, const bf16_t* __restrict__ Wvb,
    float* __restrict__ Qb, float* __restrict__ Kb, float* __restrict__ Vb)
{
    __shared__ bf16_t As[64 * LDA2];
    __shared__ bf16_t Ws[64 * LDA2];
    int t = threadIdx.x;
    int lane = t & 63, w = t >> 6;
    int wm = w & 1, wn = w >> 1;
    int ml = lane & 15, quad = lane >> 4;
    int m0 = blockIdx.x * 64;
    int wsel = blockIdx.y >> 2;
    const bf16_t* W = (wsel == 0) ? Wqb : ((wsel == 1) ? Wkb : Wvb);
    float* Ob = (wsel == 0) ? Qb : ((wsel == 1) ? Kb : Vb);
    int n0 = (blockIdx.y & 3) * 64;
    int srow = t >> 3;            // 0..31
    int scol = (t & 7) * 8;
    f32x4 acc[2][2];
    f32x4 zero = {0.f, 0.f, 0.f, 0.f};
    acc[0][0] = zero; acc[0][1] = zero; acc[1][0] = zero; acc[1][1] = zero;

    for (int k0 = 0; k0 < Hh; k0 += 64) {
        bf16x8 a[2], b[2];
        #pragma unroll
        for (int s = 0; s < 2; ++s) {
            a[s] = *(const bf16x8*)(xb + (size_t)(m0 + srow + s * 32) * Hh + k0 + scol);
            b[s] = *(const bf16x8*)(W  + (size_t)(n0 + srow + s * 32) * Hh + k0 + scol);
        }
        __syncthreads();
        #pragma unroll
        for (int s = 0; s < 2; ++s) {
            *(bf16x8*)&As[(srow + s * 32) * LDA2 + scol] = a[s];
            *(bf16x8*)&Ws[(srow + s * 32) * LDA2 + scol] = b[s];
        }
        __syncthreads();
        #pragma unroll
        for (int kk = 0; kk < 64; kk += 32) {
            bf16x8 af[2], bfr[2];
            #pragma unroll
            for (int i = 0; i < 2; ++i) {
                af[i]  = *(const bf16x8*)&As[(wm * 32 + i * 16 + ml) * LDA2 + kk + quad * 8];
                bfr[i] = *(const bf16x8*)&Ws[(wn * 32 + i * 16 + ml) * LDA2 + kk + quad * 8];
            }
            #pragma unroll
            for (int i = 0; i < 2; ++i)
                #pragma unroll
                for (int j = 0; j < 2; ++j)
                    acc[i][j] = __builtin_amdgcn_mfma_f32_16x16x32_bf16(af[i], bfr[j], acc[i][j], 0, 0, 0);
        }
    }
    #pragma unroll
    for (int i = 0; i < 2; ++i)
        #pragma unroll
        for (int j = 0; j < 2; ++j)
            #pragma unroll
            for (int r = 0; r < 4; ++r) {
                int mg = m0 + wm * 32 + i * 16 + quad * 4 + r;
                int ng = n0 + wn * 32 + j * 16 + ml;
                Ob[(size_t)mg * Hh + ng] = acc[i][j][r];
            }
}

// ---------------------------------------------------------------------------
// Sparse attention v4: one 256-thread block per (b,row). Score phase is
// wave-per-K-row (coalesced 1KB loads, 8-lane shfl dot reduce); softmax per
// (h,dl) half-wave lanes; V accumulate unrolled x4. No K staging in LDS.
// ---------------------------------------------------------------------------
__global__ __launch_bounds__(256) void attn4_kernel(
    const float* __restrict__ Qb, const float* __restrict__ Kb, const float* __restrict__ Vb,
    const unsigned int* __restrict__ mask, float* __restrict__ attn)
{
    __shared__ unsigned short nbr[Nn];   // 4 KB: dedup'd neighbor list
    __shared__ float qs[Hh];             // 1 KB
    __shared__ float sraw[32 * 9];       // scores [r*9 + h], padded
    __shared__ float scw[Hh];            // weights [h*32 + dl]
    __shared__ int nn_sh;
    int gid = blockIdx.x;
    int i = gid & (Nn - 1);
    int b = gid >> 11;
    int t = threadIdx.x;
    int h = t >> 5, dl = t & 31;
    int w = t >> 6, lane = t & 63;

    if (t < 64) {   // wave 0: extract dedup'd neighbor list from bitmask
        unsigned int bits = mask[i * MW + t];
        int cnt = __popc(bits);
        int incl = cnt;
        #pragma unroll
        for (int off = 1; off < 64; off <<= 1) {
            int v = __shfl_up(incl, off, 64);
            if (t >= off) incl += v;
        }
        int idx = incl - cnt;
        unsigned int bb = bits;
        while (bb) {
            int bit = __ffs(bb) - 1;
            nbr[idx++] = (unsigned short)(t * 32 + bit);
            bb &= bb - 1;
        }
        if (t == 63) nn_sh = incl;
    }
    qs[t] = Qb[((size_t)((b << 11) + i)) * Hh + t];
    __syncthreads();
    int nn = nn_sh;

    float m_run = -1e30f, l_run = 0.f, o = 0.f;
    const float scale = 0.17677669529663687f;  // 1/sqrt(32)
    int nch = (nn + 31) >> 5;
    for (int c = 0; c < nch; ++c) {
        int base = c << 5;
        int lim = min(32, nn - base);
        // ---- score phase: wave w handles rows w, w+4, ...  (coalesced) ----
        float4 qv = *(const float4*)&qs[lane << 2];
        #pragma unroll
        for (int s = 0; s < 8; ++s) {
            int r = (s << 2) + w;
            if (r < lim) {
                int j = nbr[base + r];
                float4 kv = *(const float4*)(Kb + (((size_t)((b << 11) + j)) << 8) + (lane << 2));
                float p = fmaf(kv.x, qv.x, fmaf(kv.y, qv.y, fmaf(kv.z, qv.z, kv.w * qv.w)));
                p += __shfl_xor(p, 1, 64);
                p += __shfl_xor(p, 2, 64);
                p += __shfl_xor(p, 4, 64);
                if ((lane & 7) == 0) sraw[r * 9 + (lane >> 3)] = p * scale;
            }
        }
        __syncthreads();
        // ---- softmax: lane (h,dl) owns neighbor dl of chunk for head h ----
        float s_val = (dl < lim) ? sraw[dl * 9 + h] : -1e30f;
        float mc = s_val;
        #pragma unroll
        for (int m = 1; m < 32; m <<= 1) mc = fmaxf(mc, __shfl_xor(mc, m, 64));
        float m_new = fmaxf(m_run, mc);
        float wgt = __expf(s_val - m_new);
        float sum = wgt;
        #pragma unroll
        for (int m = 1; m < 32; m <<= 1) sum += __shfl_xor(sum, m, 64);
        float alpha = __expf(m_run - m_new);
        l_run = l_run * alpha + sum;
        m_run = m_new;
        scw[t] = wgt;
        __syncthreads();
        // ---- V accumulate (coalesced rows, 4 independent accumulators) ----
        float oc0 = 0.f, oc1 = 0.f, oc2 = 0.f, oc3 = 0.f;
        int kl = 0;
        for (; kl + 4 <= lim; kl += 4) {
            int j0 = nbr[base + kl + 0], j1 = nbr[base + kl + 1];
            int j2 = nbr[base + kl + 2], j3 = nbr[base + kl + 3];
            float w0 = scw[(h << 5) + kl + 0], w1 = scw[(h << 5) + kl + 1];
            float w2 = scw[(h << 5) + kl + 2], w3 = scw[(h << 5) + kl + 3];
            float v0 = Vb[(((size_t)((b << 11) + j0)) << 8) + t];
            float v1 = Vb[(((size_t)((b << 11) + j1)) << 8) + t];
            float v2 = Vb[(((size_t)((b << 11) + j2)) << 8) + t];
            float v3 = Vb[(((size_t)((b << 11) + j3)) << 8) + t];
            oc0 = fmaf(w0, v0, oc0); oc1 = fmaf(w1, v1, oc1);
            oc2 = fmaf(w2, v2, oc2); oc3 = fmaf(w3, v3, oc3);
        }
        for (; kl < lim; ++kl) {
            int j = nbr[base + kl];
            oc0 = fmaf(scw[(h << 5) + kl], Vb[(((size_t)((b << 11) + j)) << 8) + t], oc0);
        }
        o = o * alpha + ((oc0 + oc1) + (oc2 + oc3));
    }
    float inv = (l_run > 0.f) ? 1.f / l_run : 0.f;
    attn[((size_t)((b << 11) + i)) * Hh + t] = o * inv;
}

// ---------------------------------------------------------------------------
// out = LayerNorm(attn @ Wo^T + x): 16 full rows per block (BN=256), bf16 Wo.
// y staged in LDS (aliases the W buffer) so LN fuses into the epilogue.
// ---------------------------------------------------------------------------
__global__ __launch_bounds__(256) void out_ln_kernel(
    const float* __restrict__ attnb, const bf16_t* __restrict__ Wob,
    const float* __restrict__ x, const float* __restrict__ gamma,
    const float* __restrict__ beta, float* __restrict__ out)
{
    __shared__ bf16_t As[16 * LDA2];
    __shared__ __align__(16) char wbuf[256 * LDA2 * sizeof(bf16_t)];  // 36.9 KB
    bf16_t* Ws = (bf16_t*)wbuf;
    float* yb = (float*)wbuf;          // 16 x 260 fp32 = 16.6 KB, aliased
    int t = threadIdx.x;
    int lane = t & 63, w = t >> 6;
    int ml = lane & 15, quad = lane >> 4;
    int m0 = blockIdx.x * 16;
    f32x4 acc[4];
    f32x4 zero = {0.f, 0.f, 0.f, 0.f};
    acc[0] = zero; acc[1] = zero; acc[2] = zero; acc[3] = zero;
    int arow = t >> 4, acol = (t & 15) * 4;   // A staging: 1 float4/thread
    int wrow = t >> 3, wcol = (t & 7) * 8;    // W staging: 8 bf16x8/thread

    for (int k0 = 0; k0 < Hh; k0 += 64) {
        float4 av = *(const float4*)(attnb + (size_t)(m0 + arow) * Hh + k0 + acol);
        bf16x8 wv[8];
        #pragma unroll
        for (int s = 0; s < 8; ++s)
            wv[s] = *(const bf16x8*)(Wob + (size_t)(wrow + s * 32) * Hh + k0 + wcol);
        __syncthreads();
        bf16x4 ac = {(bf16_t)av.x, (bf16_t)av.y, (bf16_t)av.z, (bf16_t)av.w};
        *(bf16x4*)&As[arow * LDA2 + acol] = ac;
        #pragma unroll
        for (int s = 0; s < 8; ++s)
            *(bf16x8*)&Ws[(wrow + s * 32) * LDA2 + wcol] = wv[s];
        __syncthreads();
        #pragma unroll
        for (int kk = 0; kk < 64; kk += 32) {
            bf16x8 af = *(const bf16x8*)&As[ml * LDA2 + kk + quad * 8];
            #pragma unroll
            for (int ct = 0; ct < 4; ++ct) {
                bf16x8 bfr = *(const bf16x8*)&Ws[(w * 64 + ct * 16 + ml) * LDA2 + kk + quad * 8];
                acc[ct] = __builtin_amdgcn_mfma_f32_16x16x32_bf16(af, bfr, acc[ct], 0, 0, 0);
            }
        }
    }
    __syncthreads();   // all Ws reads done before aliasing as yb
    #pragma unroll
    for (int ct = 0; ct < 4; ++ct)
        #pragma unroll
        for (int r = 0; r < 4; ++r) {
            int row = quad * 4 + r;
            int col = w * 64 + ct * 16 + ml;
            yb[row * 260 + col] = acc[ct][r] + x[(size_t)(m0 + row) * Hh + col];
        }
    __syncthreads();
    // LN: wave w handles rows w*4 .. w*4+3
    for (int rr = 0; rr < 4; ++rr) {
        int row = w * 4 + rr;
        float4 v = *(const float4*)&yb[row * 260 + lane * 4];
        float sum = v.x + v.y + v.z + v.w;
        #pragma unroll
        for (int m = 1; m < 64; m <<= 1) sum += __shfl_xor(sum, m, 64);
        float mu = sum * (1.f / Hh);
        float4 d = {v.x - mu, v.y - mu, v.z - mu, v.w - mu};
        float ss = d.x * d.x + d.y * d.y + d.z * d.z + d.w * d.w;
        #pragma unroll
        for (int m = 1; m < 64; m <<= 1) ss += __shfl_xor(ss, m, 64);
        float r = rsqrtf(ss * (1.f / Hh) + LN_EPS);
        float4 g  = *(const float4*)(gamma + lane * 4);
        float4 bt = *(const float4*)(beta + lane * 4);
        float4 ov = {d.x * r * g.x + bt.x, d.y * r * g.y + bt.y,
                     d.z * r * g.z + bt.z, d.w * r * g.w + bt.w};
        *(float4*)(out + (size_t)(m0 + row) * Hh + lane * 4) = ov;
    }
}

extern "C" void kernel_launch(void* const* d_in, const int* in_sizes, int n_in,
                              void* d_out, int out_size, void* d_ws, size_t ws_size,
                              hipStream_t stream) {
    const float* x     = (const float*)d_in[0];
    const int*   ei    = (const int*)d_in[1];
    // d_in[2] = edge_weights: unused by the reference
    const float* Wq    = (const float*)d_in[3];
    const float* Wk    = (const float*)d_in[4];
    const float* Wv    = (const float*)d_in[5];
    const float* Wo    = (const float*)d_in[6];
    const float* gamma = (const float*)d_in[7];
    const float* beta  = (const float*)d_in[8];
    float* out = (float*)d_out;

    const int NTOK = Bb * Nn * Hh;  // 1048576
    float* Qb    = (float*)d_ws;
    float* Kb    = Qb + NTOK;
    float* Vb    = Kb + NTOK;
    float* attnb = Vb + NTOK;
    unsigned int* mask = (unsigned int*)(attnb + NTOK);
    bf16_t* xb  = (bf16_t*)(mask + Nn * MW);
    bf16_t* Wqb = xb + NTOK;
    bf16_t* Wkb = Wqb + Hh * Hh;
    bf16_t* Wvb = Wkb + Hh * Hh;
    bf16_t* Wob = Wvb + Hh * Hh;

    hipMemsetAsync(mask, 0, Nn * MW * sizeof(unsigned int), stream);
    hipLaunchKernelGGL(cvt_bf16_kernel, dim3(NTOK / 4 / 256, 5), dim3(256), 0, stream,
                       x, Wq, Wk, Wv, Wo, xb, Wqb, Wkb, Wvb, Wob);
    hipLaunchKernelGGL(build_mask_kernel, dim3(NEDGE / 256), dim3(256), 0, stream, ei, mask);
    hipLaunchKernelGGL(qkv_gemm2_kernel, dim3((Bb * Nn) / 64, 12), dim3(256), 0, stream,
                       xb, Wqb, Wkb, Wvb, Qb, Kb, Vb);
    hipLaunchKernelGGL(attn4_kernel, dim3(Bb * Nn), dim3(256), 0, stream,
                       Qb, Kb, Vb, mask, attnb);
    hipLaunchKernelGGL(out_ln_kernel, dim3((Bb * Nn) / 16), dim3(256), 0, stream,
                       attnb, Wob, x, gamma, beta, out);
}

// Round 5
// 116.501 us; speedup vs baseline: 3.6830x; 1.0296x over previous
//
#include <hip/hip_runtime.h>
#include <math.h>

#define Bb 2
#define Nn 2048
#define Hh 256
#define NH 8
#define HD 32
#define NEDGE 65536
#define LN_EPS 1e-5f
#define MW 64          // mask words per row = N/32

typedef __bf16 bf16_t;
typedef bf16_t bf16x8 __attribute__((ext_vector_type(8)));
typedef bf16_t bf16x4 __attribute__((ext_vector_type(4)));
typedef float f32x4 __attribute__((ext_vector_type(4)));

__global__ void build_mask_kernel(const int* __restrict__ ei, unsigned int* __restrict__ mask) {
    int e = blockIdx.x * blockDim.x + threadIdx.x;
    if (e >= NEDGE) return;
    int src = ei[e];
    int dst = ei[NEDGE + e];
    atomicOr(&mask[src * MW + (dst >> 5)], 1u << (dst & 31));
}

// fp32 -> bf16 conversion of x + 4 weights, and mask zeroing, in one pass
__global__ __launch_bounds__(256) void cvt_zero_kernel(
    const float* __restrict__ s0, const float* __restrict__ s1, const float* __restrict__ s2,
    const float* __restrict__ s3, const float* __restrict__ s4,
    bf16_t* __restrict__ d0, bf16_t* __restrict__ d1, bf16_t* __restrict__ d2,
    bf16_t* __restrict__ d3, bf16_t* __restrict__ d4,
    uint4* __restrict__ mask4)
{
    int which = blockIdx.y;
    int i = blockIdx.x * blockDim.x + threadIdx.x;
    if (which == 5) {
        if (i < Nn * MW / 4) mask4[i] = make_uint4(0, 0, 0, 0);
        return;
    }
    const float* s = (which == 0) ? s0 : (which == 1) ? s1 : (which == 2) ? s2 : (which == 3) ? s3 : s4;
    bf16_t* d = (which == 0) ? d0 : (which == 1) ? d1 : (which == 2) ? d2 : (which == 3) ? d3 : d4;
    int n4 = (which == 0) ? (Bb * Nn * Hh / 4) : (Hh * Hh / 4);
    if (i >= n4) return;
    float4 v = ((const float4*)s)[i];
    bf16x4 o = {(bf16_t)v.x, (bf16_t)v.y, (bf16_t)v.z, (bf16_t)v.w};
    ((bf16x4*)d)[i] = o;
}

// ---------------------------------------------------------------------------
// bf16 MFMA GEMM: 64x64 tile, BK=64, 4 waves 2x2. Q stored fp32; K,V bf16.
// ---------------------------------------------------------------------------
#define LDA2 72

__global__ __launch_bounds__(256) void qkv_gemm3_kernel(
    const bf16_t* __restrict__ xb,
    const bf16_t* __restrict__ Wqb, const bf16_t* __restrict__ Wkb, const bf16_t* __restrict__ Wvb,
    float* __restrict__ Qb, bf16_t* __restrict__ Kb16, bf16_t* __restrict__ Vb16)
{
    __shared__ bf16_t As[64 * LDA2];
    __shared__ bf16_t Ws[64 * LDA2];
    int t = threadIdx.x;
    int lane = t & 63, w = t >> 6;
    int wm = w & 1, wn = w >> 1;
    int ml = lane & 15, quad = lane >> 4;
    int m0 = blockIdx.x * 64;
    int wsel = blockIdx.y >> 2;
    const bf16_t* W = (wsel == 0) ? Wqb : ((wsel == 1) ? Wkb : Wvb);
    int n0 = (blockIdx.y & 3) * 64;
    int srow = t >> 3;
    int scol = (t & 7) * 8;
    f32x4 acc[2][2];
    f32x4 zero = {0.f, 0.f, 0.f, 0.f};
    acc[0][0] = zero; acc[0][1] = zero; acc[1][0] = zero; acc[1][1] = zero;

    for (int k0 = 0; k0 < Hh; k0 += 64) {
        bf16x8 a[2], b[2];
        #pragma unroll
        for (int s = 0; s < 2; ++s) {
            a[s] = *(const bf16x8*)(xb + (size_t)(m0 + srow + s * 32) * Hh + k0 + scol);
            b[s] = *(const bf16x8*)(W  + (size_t)(n0 + srow + s * 32) * Hh + k0 + scol);
        }
        __syncthreads();
        #pragma unroll
        for (int s = 0; s < 2; ++s) {
            *(bf16x8*)&As[(srow + s * 32) * LDA2 + scol] = a[s];
            *(bf16x8*)&Ws[(srow + s * 32) * LDA2 + scol] = b[s];
        }
        __syncthreads();
        #pragma unroll
        for (int kk = 0; kk < 64; kk += 32) {
            bf16x8 af[2], bfr[2];
            #pragma unroll
            for (int i = 0; i < 2; ++i) {
                af[i]  = *(const bf16x8*)&As[(wm * 32 + i * 16 + ml) * LDA2 + kk + quad * 8];
                bfr[i] = *(const bf16x8*)&Ws[(wn * 32 + i * 16 + ml) * LDA2 + kk + quad * 8];
            }
            #pragma unroll
            for (int i = 0; i < 2; ++i)
                #pragma unroll
                for (int j = 0; j < 2; ++j)
                    acc[i][j] = __builtin_amdgcn_mfma_f32_16x16x32_bf16(af[i], bfr[j], acc[i][j], 0, 0, 0);
        }
    }
    bf16_t* Ob16 = (wsel == 1) ? Kb16 : Vb16;
    #pragma unroll
    for (int i = 0; i < 2; ++i)
        #pragma unroll
        for (int j = 0; j < 2; ++j)
            #pragma unroll
            for (int r = 0; r < 4; ++r) {
                int mg = m0 + wm * 32 + i * 16 + quad * 4 + r;
                int ng = n0 + wn * 32 + j * 16 + ml;
                float v = acc[i][j][r];
                if (wsel == 0) Qb[(size_t)mg * Hh + ng] = v;
                else           Ob16[(size_t)mg * Hh + ng] = (bf16_t)v;
            }
}

// ---------------------------------------------------------------------------
// Sparse attention v5: block per (b,row). Score: wave-per-K-row, bf16x4/lane.
// V phase: 4 waves process 4 neighbor rows concurrently, bf16x4 (4 cols) per
// thread, per-wave partials merged via LDS at the end.
// ---------------------------------------------------------------------------
__global__ __launch_bounds__(256) void attn5_kernel(
    const float* __restrict__ Qb, const bf16_t* __restrict__ Kb16, const bf16_t* __restrict__ Vb16,
    const unsigned int* __restrict__ mask, float* __restrict__ attnb)
{
    __shared__ unsigned short nbr[Nn];   // 4 KB
    __shared__ float qs[Hh];
    __shared__ float sraw[32 * 9];
    __shared__ float scw[Hh];
    __shared__ float alpha_l[NH];
    __shared__ float linv_l[NH];
    __shared__ float obuf[4][Hh];        // 4 KB
    __shared__ int nn_sh;
    int gid = blockIdx.x;
    int i = gid & (Nn - 1);
    int b = gid >> 11;
    int t = threadIdx.x;
    int h = t >> 5, dl = t & 31;
    int w = t >> 6, lane = t & 63;
    int hw = lane >> 3;                  // head owning cols 4*lane..4*lane+3

    if (t < 64) {   // wave 0: extract dedup'd neighbor list from bitmask
        unsigned int bits = mask[i * MW + t];
        int cnt = __popc(bits);
        int incl = cnt;
        #pragma unroll
        for (int off = 1; off < 64; off <<= 1) {
            int v = __shfl_up(incl, off, 64);
            if (t >= off) incl += v;
        }
        int idx = incl - cnt;
        unsigned int bb = bits;
        while (bb) {
            int bit = __ffs(bb) - 1;
            nbr[idx++] = (unsigned short)(t * 32 + bit);
            bb &= bb - 1;
        }
        if (t == 63) nn_sh = incl;
    }
    qs[t] = Qb[((size_t)((b << 11) + i)) * Hh + t];
    __syncthreads();
    int nn = nn_sh;

    float m_run = -1e30f, l_run = 0.f;
    float o0 = 0.f, o1 = 0.f, o2 = 0.f, o3 = 0.f;
    const float scale = 0.17677669529663687f;  // 1/sqrt(32)
    int nch = (nn + 31) >> 5;
    for (int c = 0; c < nch; ++c) {
        int base = c << 5;
        int lim = min(32, nn - base);
        // ---- scores: wave w rows w, w+4, ...; lane covers dims 4l..4l+3 ----
        float4 qv = *(const float4*)&qs[lane << 2];
        #pragma unroll
        for (int s = 0; s < 8; ++s) {
            int r = (s << 2) + w;
            if (r < lim) {
                int j = nbr[base + r];
                bf16x4 kv = *(const bf16x4*)(Kb16 + (((size_t)((b << 11) + j)) << 8) + (lane << 2));
                float p = fmaf((float)kv.x, qv.x, fmaf((float)kv.y, qv.y,
                          fmaf((float)kv.z, qv.z, (float)kv.w * qv.w)));
                p += __shfl_xor(p, 1, 64);
                p += __shfl_xor(p, 2, 64);
                p += __shfl_xor(p, 4, 64);
                if ((lane & 7) == 0) sraw[r * 9 + (lane >> 3)] = p * scale;
            }
        }
        __syncthreads();
        // ---- softmax in (h,dl) layout ----
        float s_val = (dl < lim) ? sraw[dl * 9 + h] : -1e30f;
        float mc = s_val;
        #pragma unroll
        for (int m = 1; m < 32; m <<= 1) mc = fmaxf(mc, __shfl_xor(mc, m, 64));
        float m_new = fmaxf(m_run, mc);
        float wgt = __expf(s_val - m_new);
        float sum = wgt;
        #pragma unroll
        for (int m = 1; m < 32; m <<= 1) sum += __shfl_xor(sum, m, 64);
        float alpha = __expf(m_run - m_new);
        l_run = l_run * alpha + sum;
        m_run = m_new;
        scw[t] = wgt;
        if (dl == 0) alpha_l[h] = alpha;
        __syncthreads();
        // ---- V phase: wave w rows w, w+4, ...; thread covers 4 cols ----
        float av = alpha_l[hw];
        o0 *= av; o1 *= av; o2 *= av; o3 *= av;
        #pragma unroll
        for (int s = 0; s < 8; ++s) {
            int r = (s << 2) + w;
            if (r < lim) {
                int j = nbr[base + r];
                float wg = scw[(hw << 5) + r];
                bf16x4 vv = *(const bf16x4*)(Vb16 + (((size_t)((b << 11) + j)) << 8) + (lane << 2));
                o0 = fmaf(wg, (float)vv.x, o0);
                o1 = fmaf(wg, (float)vv.y, o1);
                o2 = fmaf(wg, (float)vv.z, o2);
                o3 = fmaf(wg, (float)vv.w, o3);
            }
        }
    }
    if (dl == 0) linv_l[h] = (l_run > 0.f) ? 1.f / l_run : 0.f;
    obuf[w][(lane << 2) + 0] = o0;
    obuf[w][(lane << 2) + 1] = o1;
    obuf[w][(lane << 2) + 2] = o2;
    obuf[w][(lane << 2) + 3] = o3;
    __syncthreads();
    float val = obuf[0][t] + obuf[1][t] + obuf[2][t] + obuf[3][t];
    attnb[(((size_t)((b << 11) + i)) << 8) + t] = val * linv_l[t >> 5];
}

// ---------------------------------------------------------------------------
// out = LayerNorm(attn @ Wo^T + x): 16 full rows per block, bf16 Wo.
// ---------------------------------------------------------------------------
__global__ __launch_bounds__(256) void out_ln_kernel(
    const float* __restrict__ attnb, const bf16_t* __restrict__ Wob,
    const float* __restrict__ x, const float* __restrict__ gamma,
    const float* __restrict__ beta, float* __restrict__ out)
{
    __shared__ bf16_t As[16 * LDA2];
    __shared__ __align__(16) char wbuf[256 * LDA2 * sizeof(bf16_t)];  // 36.9 KB
    bf16_t* Ws = (bf16_t*)wbuf;
    float* yb = (float*)wbuf;          // 16 x 260 fp32, aliased after use
    int t = threadIdx.x;
    int lane = t & 63, w = t >> 6;
    int ml = lane & 15, quad = lane >> 4;
    int m0 = blockIdx.x * 16;
    f32x4 acc[4];
    f32x4 zero = {0.f, 0.f, 0.f, 0.f};
    acc[0] = zero; acc[1] = zero; acc[2] = zero; acc[3] = zero;
    int arow = t >> 4, acol = (t & 15) * 4;
    int wrow = t >> 3, wcol = (t & 7) * 8;

    for (int k0 = 0; k0 < Hh; k0 += 64) {
        float4 av = *(const float4*)(attnb + (size_t)(m0 + arow) * Hh + k0 + acol);
        bf16x8 wv[8];
        #pragma unroll
        for (int s = 0; s < 8; ++s)
            wv[s] = *(const bf16x8*)(Wob + (size_t)(wrow + s * 32) * Hh + k0 + wcol);
        __syncthreads();
        bf16x4 ac = {(bf16_t)av.x, (bf16_t)av.y, (bf16_t)av.z, (bf16_t)av.w};
        *(bf16x4*)&As[arow * LDA2 + acol] = ac;
        #pragma unroll
        for (int s = 0; s < 8; ++s)
            *(bf16x8*)&Ws[(wrow + s * 32) * LDA2 + wcol] = wv[s];
        __syncthreads();
        #pragma unroll
        for (int kk = 0; kk < 64; kk += 32) {
            bf16x8 af = *(const bf16x8*)&As[ml * LDA2 + kk + quad * 8];
            #pragma unroll
            for (int ct = 0; ct < 4; ++ct) {
                bf16x8 bfr = *(const bf16x8*)&Ws[(w * 64 + ct * 16 + ml) * LDA2 + kk + quad * 8];
                acc[ct] = __builtin_amdgcn_mfma_f32_16x16x32_bf16(af, bfr, acc[ct], 0, 0, 0);
            }
        }
    }
    __syncthreads();   // all Ws reads done before aliasing as yb
    #pragma unroll
    for (int ct = 0; ct < 4; ++ct)
        #pragma unroll
        for (int r = 0; r < 4; ++r) {
            int row = quad * 4 + r;
            int col = w * 64 + ct * 16 + ml;
            yb[row * 260 + col] = acc[ct][r] + x[(size_t)(m0 + row) * Hh + col];
        }
    __syncthreads();
    for (int rr = 0; rr < 4; ++rr) {
        int row = w * 4 + rr;
        float4 v = *(const float4*)&yb[row * 260 + lane * 4];
        float sum = v.x + v.y + v.z + v.w;
        #pragma unroll
        for (int m = 1; m < 64; m <<= 1) sum += __shfl_xor(sum, m, 64);
        float mu = sum * (1.f / Hh);
        float4 d = {v.x - mu, v.y - mu, v.z - mu, v.w - mu};
        float ss = d.x * d.x + d.y * d.y + d.z * d.z + d.w * d.w;
        #pragma unroll
        for (int m = 1; m < 64; m <<= 1) ss += __shfl_xor(ss, m, 64);
        float r = rsqrtf(ss * (1.f / Hh) + LN_EPS);
        float4 g  = *(const float4*)(gamma + lane * 4);
        float4 bt = *(const float4*)(beta + lane * 4);
        float4 ov = {d.x * r * g.x + bt.x, d.y * r * g.y + bt.y,
                     d.z * r * g.z + bt.z, d.w * r * g.w + bt.w};
        *(float4*)(out + (size_t)(m0 + row) * Hh + lane * 4) = ov;
    }
}

extern "C" void kernel_launch(void* const* d_in, const int* in_sizes, int n_in,
                              void* d_out, int out_size, void* d_ws, size_t ws_size,
                              hipStream_t stream) {
    const float* x     = (const float*)d_in[0];
    const int*   ei    = (const int*)d_in[1];
    // d_in[2] = edge_weights: unused by the reference
    const float* Wq    = (const float*)d_in[3];
    const float* Wk    = (const float*)d_in[4];
    const float* Wv    = (const float*)d_in[5];
    const float* Wo    = (const float*)d_in[6];
    const float* gamma = (const float*)d_in[7];
    const float* beta  = (const float*)d_in[8];
    float* out = (float*)d_out;

    const int NTOK = Bb * Nn * Hh;  // 1048576
    float*  Qb    = (float*)d_ws;
    bf16_t* Kb16  = (bf16_t*)(Qb + NTOK);
    bf16_t* Vb16  = Kb16 + NTOK;
    float*  attnb = (float*)(Vb16 + NTOK);
    unsigned int* mask = (unsigned int*)(attnb + NTOK);
    bf16_t* xb  = (bf16_t*)(mask + Nn * MW);
    bf16_t* Wqb = xb + NTOK;
    bf16_t* Wkb = Wqb + Hh * Hh;
    bf16_t* Wvb = Wkb + Hh * Hh;
    bf16_t* Wob = Wvb + Hh * Hh;

    hipLaunchKernelGGL(cvt_zero_kernel, dim3(NTOK / 4 / 256, 6), dim3(256), 0, stream,
                       x, Wq, Wk, Wv, Wo, xb, Wqb, Wkb, Wvb, Wob, (uint4*)mask);
    hipLaunchKernelGGL(build_mask_kernel, dim3(NEDGE / 256), dim3(256), 0, stream, ei, mask);
    hipLaunchKernelGGL(qkv_gemm3_kernel, dim3((Bb * Nn) / 64, 12), dim3(256), 0, stream,
                       xb, Wqb, Wkb, Wvb, Qb, Kb16, Vb16);
    hipLaunchKernelGGL(attn5_kernel, dim3(Bb * Nn), dim3(256), 0, stream,
                       Qb, Kb16, Vb16, mask, attnb);
    hipLaunchKernelGGL(out_ln_kernel, dim3((Bb * Nn) / 16), dim3(256), 0, stream,
                       attnb, Wob, x, gamma, beta, out);
}